// Round 8
// baseline (453.659 us; speedup 1.0000x reference)
//
#include <hip/hip_runtime.h>
#include <math.h>

// Tsit5 tableau
#define A21f 0.161f
#define A31f -0.008480655492356989f
#define A32f 0.335480655492357f
#define A41f 2.8971530571054935f
#define A42f -6.359448489975075f
#define A43f 4.3622954328695815f
#define A51f 5.325864828439257f
#define A52f -11.748883564062828f
#define A53f 7.4955393428898365f
#define A54f -0.09249506636175525f
#define A61f 5.86145544294642f
#define A62f -12.92096931784711f
#define A63f 8.159367898576159f
#define A64f -0.071584973281401f
#define A65f -0.028269050394068383f
#define B1f 0.09646076681806523f
#define B2f 0.01f
#define B3f 0.4798896504144996f
#define B4f 1.379008574103742f
#define B5f -3.290069515436081f
#define B6f 2.324710524099774f
#define E1f -0.00178001105222577714f
#define E2f -0.0008164344596567469f
#define E3f 0.007880878010261995f
#define E4f -0.1447110071732629f
#define E5f 0.5823571654525552f
#define E6f -0.45808210592918697f
#define E7f 0.015151515151515152f

#define WPB 4  // waves per block

// Fused rotate+FMA: acc += (row_ror:N of v) * w — ONE VALU inst (VOP2 DPP).
#define FMAC_RR(acc, v, w, N)                                              \
    asm("v_fmac_f32_dpp %0, %1, %2 row_ror:" #N " row_mask:0xf bank_mask:0xf" \
        : "+v"(acc) : "v"(v), "v"(w))

// s = ror_N(s) + s  (in-row rotation add on the VALU pipe)
#define ADD_RR(s, N)                                                       \
    asm("v_add_f32_dpp %0, %1, %0 row_ror:" #N " row_mask:0xf bank_mask:0xf" \
        : "+v"(s) : "v"(s))

// Full 16-long systolic dot, result complete IN-LANE (no reduction needed):
// W[k] gathered so W[k] * (row_ror:k of v) pairs the right matrix element.
#define DOT16F(acc, W, v) do {           \
    acc = fmaf((W)[0], (v), acc);        \
    FMAC_RR(acc, v, (W)[1], 1);          \
    FMAC_RR(acc, v, (W)[2], 2);          \
    FMAC_RR(acc, v, (W)[3], 3);          \
    FMAC_RR(acc, v, (W)[4], 4);          \
    FMAC_RR(acc, v, (W)[5], 5);          \
    FMAC_RR(acc, v, (W)[6], 6);          \
    FMAC_RR(acc, v, (W)[7], 7);          \
    FMAC_RR(acc, v, (W)[8], 8);          \
    FMAC_RR(acc, v, (W)[9], 9);          \
    FMAC_RR(acc, v, (W)[10], 10);        \
    FMAC_RR(acc, v, (W)[11], 11);        \
    FMAC_RR(acc, v, (W)[12], 12);        \
    FMAC_RR(acc, v, (W)[13], 13);        \
    FMAC_RR(acc, v, (W)[14], 14);        \
    FMAC_RR(acc, v, (W)[15], 15);        \
} while (0)

// softplus(x) = max(x,0) + ln2 * log2(1 + 2^(-|x|*log2e))  (hw exp2/log2)
__device__ __forceinline__ float sp(float x) {
    float t = exp2f(-fabsf(x) * 1.44269504088896341f);
    return fmaxf(x, 0.0f) + 0.69314718055994531f * __log2f(1.0f + t);
}

// State layout: each 16-lane row holds the FULL 64-vector, replicated x4.
// Lane (g,p) regs: y[q] = y[16q+p]. All rows bitwise-identical at all times
// (same data, same ops) -> every dot is row-local (DPP), f() needs only
// 4 shfl_xor(16) half-exchanges, and the error-norm reduction is pure DPP.
__global__ __launch_bounds__(256)
__attribute__((amdgpu_waves_per_eu(1, 4)))
void ode_kernel(const float* __restrict__ x0s,
                const float* __restrict__ W1, const float* __restrict__ b1,
                const float* __restrict__ W2, const float* __restrict__ b2,
                const float* __restrict__ W3, const float* __restrict__ b3,
                const void* __restrict__ Tptr,
                float* __restrict__ out, int out_size, int B)
{
    const int wave = threadIdx.x >> 6;
    const int lane = threadIdx.x & 63;
    const int traj = blockIdx.x * WPB + wave;
    if (traj >= B) return;

    const int p  = lane & 15;   // position within 16-lane DPP row
    const int g  = lane >> 4;   // row 0..3
    const int ga = g & 1;

    // output rows this lane computes: o1 (L1 & L2), c0/c1 (L3)
    const int o1 = 16 * ga + p;
    const int c0 = o1;          // f-output component 16*ga+p
    const int c1 = 32 + o1;     // f-output component 32+16*ga+p

    // ---- one-time per-lane weight gathers in DPP-rotated order ----
    // 160 floats/lane -> true VGPRs (waves_per_eu(1,4): RA budget 512).
    float W1L[4][16], W2L[2][16], W3L[2][2][16];
#pragma unroll
    for (int k = 0; k < 16; ++k) {
        const int c = (p + k) & 15;
        W1L[0][k] = W1[o1 * 64 + c];
        W1L[1][k] = W1[o1 * 64 + 16 + c];
        W1L[2][k] = W1[o1 * 64 + 32 + c];
        W1L[3][k] = W1[o1 * 64 + 48 + c];
        W2L[0][k] = W2[o1 * 32 + c];
        W2L[1][k] = W2[o1 * 32 + 16 + c];
        W3L[0][0][k] = W3[c0 * 32 + c];
        W3L[0][1][k] = W3[c0 * 32 + 16 + c];
        W3L[1][0][k] = W3[c1 * 32 + c];
        W3L[1][1][k] = W3[c1 * 32 + 16 + c];
    }
#pragma unroll
    for (int k = 0; k < 16; ++k) {
        asm("" : "+v"(W1L[0][k]), "+v"(W1L[1][k]), "+v"(W1L[2][k]), "+v"(W1L[3][k]));
        asm("" : "+v"(W2L[0][k]), "+v"(W2L[1][k]));
        asm("" : "+v"(W3L[0][0][k]), "+v"(W3L[0][1][k]), "+v"(W3L[1][0][k]), "+v"(W3L[1][1][k]));
    }
    const float b1L = b1[o1], b2L = b2[o1];
    const float b3c0 = b3[c0], b3c1 = b3[c1];

    // f: u[q]=u[16q+p] replicated-by-row -> r[q] same layout.
    auto f = [&](const float* u, float* r) {
        // L1: full 64-dot in-lane (4 systolic chains)
        float a0 = 0.f, a1 = 0.f, a2 = 0.f, a3 = 0.f;
        DOT16F(a0, W1L[0], u[0]);
        DOT16F(a1, W1L[1], u[1]);
        DOT16F(a2, W1L[2], u[2]);
        DOT16F(a3, W1L[3], u[3]);
        float h1 = sp(((a0 + a1) + (a2 + a3)) + b1L);   // h1[o1]
        float oth = __shfl_xor(h1, 16);                 // complementary half
        float hA = ga ? oth : h1;                       // h1[p]
        float hB = ga ? h1 : oth;                       // h1[16+p]
        // L2: full 32-dot in-lane
        float s0 = 0.f, s1 = 0.f;
        DOT16F(s0, W2L[0], hA);
        DOT16F(s1, W2L[1], hB);
        float h2 = sp((s0 + s1) + b2L);                 // h2[o1]
        float oth2 = __shfl_xor(h2, 16);
        float gA = ga ? oth2 : h2;                      // h2[p]
        float gB = ga ? h2 : oth2;                      // h2[16+p]
        // L3: two full 32-dots in-lane (components c0, c1)
        float t00 = 0.f, t01 = 0.f, t10 = 0.f, t11 = 0.f;
        DOT16F(t00, W3L[0][0], gA);
        DOT16F(t01, W3L[0][1], gB);
        DOT16F(t10, W3L[1][0], gA);
        DOT16F(t11, W3L[1][1], gB);
        float rc0 = (t00 + t01) + b3c0;   // f[16*ga+p]
        float rc1 = (t10 + t11) + b3c1;   // f[32+16*ga+p]
        float e0 = __shfl_xor(rc0, 16);
        float e1 = __shfl_xor(rc1, 16);
        r[0] = ga ? e0 : rc0;    // f[p]
        r[1] = ga ? rc0 : e0;    // f[16+p]
        r[2] = ga ? e1 : rc1;    // f[32+p]
        r[3] = ga ? rc1 : e1;    // f[48+p]
    };

    int ti = *(const int*)Tptr;
    float Tf = (ti > 0 && ti < 1000000) ? (float)ti : *(const float*)Tptr;
    const float ts_step = Tf / 10.0f;

    float y[4];
#pragma unroll
    for (int q = 0; q < 4; ++q) y[q] = x0s[traj * 64 + 16 * q + p];

    // coalesced snapshot: lane l writes y[l] = reg q=g
    {
        float lo = ga ? y[1] : y[0];
        float hi = ga ? y[3] : y[2];
        out[traj * 704 + lane] = (g & 2) ? hi : lo;
    }

    float t = 0.0f;
    float dt = 1e-3f;
    int n = 0;

    float k1v[4];
    f(y, k1v);  // FSAL seed

    for (int iv = 1; iv <= 10; ++iv) {
        const float t_target = (iv == 10) ? Tf : ts_step * (float)iv;
        for (int it = 0; it < 64; ++it) {
            const float remaining = t_target - t;
            if (remaining <= 1e-12f) break;
            const float h = fminf(dt, fmaxf(remaining, 0.0f));

            float a[4], k2v[4], k3v[4], k4v[4], k5v[4], k6v[4], k7v[4], y5[4], ev[4];
            const float c21 = h * A21f;
#pragma unroll
            for (int q = 0; q < 4; ++q) a[q] = fmaf(c21, k1v[q], y[q]);
            f(a, k2v);
            const float c31 = h * A31f, c32 = h * A32f;
#pragma unroll
            for (int q = 0; q < 4; ++q) a[q] = fmaf(c32, k2v[q], fmaf(c31, k1v[q], y[q]));
            f(a, k3v);
            const float c41 = h * A41f, c42 = h * A42f, c43 = h * A43f;
#pragma unroll
            for (int q = 0; q < 4; ++q)
                a[q] = fmaf(c43, k3v[q], fmaf(c42, k2v[q], fmaf(c41, k1v[q], y[q])));
            f(a, k4v);
            const float c51 = h * A51f, c52 = h * A52f, c53 = h * A53f, c54 = h * A54f;
#pragma unroll
            for (int q = 0; q < 4; ++q)
                a[q] = fmaf(c54, k4v[q], fmaf(c53, k3v[q], fmaf(c52, k2v[q], fmaf(c51, k1v[q], y[q]))));
            f(a, k5v);
            const float c61 = h * A61f, c62 = h * A62f, c63 = h * A63f, c64 = h * A64f, c65 = h * A65f;
#pragma unroll
            for (int q = 0; q < 4; ++q)
                a[q] = fmaf(c65, k5v[q], fmaf(c64, k4v[q], fmaf(c63, k3v[q],
                        fmaf(c62, k2v[q], fmaf(c61, k1v[q], y[q])))));
            f(a, k6v);
            const float d1 = h * B1f, d2 = h * B2f, d3 = h * B3f, d4 = h * B4f, d5 = h * B5f, d6 = h * B6f;
#pragma unroll
            for (int q = 0; q < 4; ++q)
                y5[q] = fmaf(d6, k6v[q], fmaf(d5, k5v[q], fmaf(d4, k4v[q],
                         fmaf(d3, k3v[q], fmaf(d2, k2v[q], fmaf(d1, k1v[q], y[q]))))));
            f(y5, k7v);
            const float e1c = h * E1f, e2c = h * E2f, e3c = h * E3f, e4c = h * E4f,
                        e5c = h * E5f, e6c = h * E6f, e7c = h * E7f;
            float s = 0.f;
#pragma unroll
            for (int q = 0; q < 4; ++q) {
                ev[q] = fmaf(e7c, k7v[q], fmaf(e6c, k6v[q], fmaf(e5c, k5v[q],
                         fmaf(e4c, k4v[q], fmaf(e3c, k3v[q], fmaf(e2c, k2v[q],
                         e1c * k1v[q]))))));
                float scl = 1e-6f + 1e-3f * fmaxf(fabsf(y[q]), fabsf(y5[q]));
                float rr_ = ev[q] / scl;
                s = fmaf(rr_, rr_, s);
            }
            // In-row butterfly, ror order 8,4,2,1 — NOT 1,2,4,8.
            // Proof of lane-uniformity: after ror:8, s[p]==s[(p+8)%16] bitwise
            // (IEEE add is commutative). Inductively each later stage adds
            // operands that are bitwise-equal across the lane class, so after
            // ror:1 all 16 lanes hold the identical rounded sum. Rows are
            // identical by state replication -> enorm is wave-uniform and
            // control flow cannot diverge (round-6 lesson: 1,2,4,8 cyclic
            // order broke this and cost +47%).
            ADD_RR(s, 8);
            ADD_RR(s, 4);
            ADD_RR(s, 2);
            ADD_RR(s, 1);
            float enorm = fmaxf(sqrtf(s * (1.0f / 64.0f)), 1e-10f);

            bool accept = enorm <= 1.0f;
            float fac = 0.9f * exp2f(-0.2f * __log2f(enorm));  // 0.9*enorm^-0.2
            fac = fminf(fmaxf(fac, 0.1f), 5.0f);

            if (accept) {
                t += h;
#pragma unroll
                for (int q = 0; q < 4; ++q) { y[q] = y5[q]; k1v[q] = k7v[q]; }
            }
            dt = fmaxf(h * fac, 1e-8f);
            ++n;
        }
        {
            float lo = ga ? y[1] : y[0];
            float hi = ga ? y[3] : y[2];
            out[traj * 704 + iv * 64 + lane] = (g & 2) ? hi : lo;
        }
    }

    if (lane == 0) atomicAdd(out + (out_size - 1), (float)n);
}

__global__ void init_n(float* p) { *p = 0.0f; }

extern "C" void kernel_launch(void* const* d_in, const int* in_sizes, int n_in,
                              void* d_out, int out_size, void* d_ws, size_t ws_size,
                              hipStream_t stream) {
    const float* x0s = (const float*)d_in[0];
    const float* W1  = (const float*)d_in[1];
    const float* b1  = (const float*)d_in[2];
    const float* W2  = (const float*)d_in[3];
    const float* b2  = (const float*)d_in[4];
    const float* W3  = (const float*)d_in[5];
    const float* b3  = (const float*)d_in[6];
    const void*  Tp  = d_in[7];
    float* out = (float*)d_out;

    const int B = in_sizes[0] / 64;
    const int grid = (B + WPB - 1) / WPB;

    init_n<<<1, 1, 0, stream>>>(out + (out_size - 1));
    ode_kernel<<<grid, 256, 0, stream>>>(x0s, W1, b1, W2, b2, W3, b3, Tp,
                                         out, out_size, B);
}

// Round 9
// 200.481 us; speedup vs baseline: 2.2629x; 2.2629x over previous
//
#include <hip/hip_runtime.h>
#include <math.h>

// Tsit5 tableau
#define A21f 0.161f
#define A31f -0.008480655492356989f
#define A32f 0.335480655492357f
#define A41f 2.8971530571054935f
#define A42f -6.359448489975075f
#define A43f 4.3622954328695815f
#define A51f 5.325864828439257f
#define A52f -11.748883564062828f
#define A53f 7.4955393428898365f
#define A54f -0.09249506636175525f
#define A61f 5.86145544294642f
#define A62f -12.92096931784711f
#define A63f 8.159367898576159f
#define A64f -0.071584973281401f
#define A65f -0.028269050394068383f
#define B1f 0.09646076681806523f
#define B2f 0.01f
#define B3f 0.4798896504144996f
#define B4f 1.379008574103742f
#define B5f -3.290069515436081f
#define B6f 2.324710524099774f
#define E1f -0.00178001105222577714f
#define E2f -0.0008164344596567469f
#define E3f 0.007880878010261995f
#define E4f -0.1447110071732629f
#define E5f 0.5823571654525552f
#define E6f -0.45808210592918697f
#define E7f 0.015151515151515152f

#define WPB 4  // waves per block

// Fused rotate+FMA: acc += (row_ror:N of v) * w — ONE VALU inst (VOP2 DPP).
#define FMAC_RR(acc, v, w, N)                                              \
    asm("v_fmac_f32_dpp %0, %1, %2 row_ror:" #N " row_mask:0xf bank_mask:0xf" \
        : "+v"(acc) : "v"(v), "v"(w))

// Half-dots: 8-deep fmac chains.
#define DOT8_LO(acc, W, v) do {          \
    acc = fmaf((W)[0], (v), acc);        \
    FMAC_RR(acc, v, (W)[1], 1);          \
    FMAC_RR(acc, v, (W)[2], 2);          \
    FMAC_RR(acc, v, (W)[3], 3);          \
    FMAC_RR(acc, v, (W)[4], 4);          \
    FMAC_RR(acc, v, (W)[5], 5);          \
    FMAC_RR(acc, v, (W)[6], 6);          \
    FMAC_RR(acc, v, (W)[7], 7);          \
} while (0)
#define DOT8_HI(acc, W, v) do {          \
    FMAC_RR(acc, v, (W)[8], 8);          \
    FMAC_RR(acc, v, (W)[9], 9);          \
    FMAC_RR(acc, v, (W)[10], 10);        \
    FMAC_RR(acc, v, (W)[11], 11);        \
    FMAC_RR(acc, v, (W)[12], 12);        \
    FMAC_RR(acc, v, (W)[13], 13);        \
    FMAC_RR(acc, v, (W)[14], 14);        \
    FMAC_RR(acc, v, (W)[15], 15);        \
} while (0)

// softplus(x) = max(x,0) + ln2 * log2(1 + 2^(-|x|*log2e))  (hw exp2/log2)
__device__ __forceinline__ float sp(float x) {
    float t = exp2f(-fabsf(x) * 1.44269504088896341f);
    return fmaxf(x, 0.0f) + 0.69314718055994531f * __log2f(1.0f + t);
}

// DUAL-TRAJECTORY wave: each wave integrates 2 independent trajectories,
// interleaved in one instruction stream — chain A's DS/dependency stalls are
// covered by chain B (round-8 lesson: more ILP, but WITHOUT blowing the
// register file: weights shared, 80/lane). At 2 waves/SIMD the VGPR budget
// is 256, so weights live in TRUE VGPRs (no AGPR-read tax of rounds 3-7).
__global__ __launch_bounds__(256)
__attribute__((amdgpu_waves_per_eu(2, 2)))
void ode_kernel(const float* __restrict__ x0s,
                const float* __restrict__ W1, const float* __restrict__ b1,
                const float* __restrict__ W2, const float* __restrict__ b2,
                const float* __restrict__ W3, const float* __restrict__ b3,
                const void* __restrict__ Tptr,
                float* __restrict__ out, int out_size, int B)
{
    const int wave = threadIdx.x >> 6;
    const int lane = threadIdx.x & 63;
    const int wid  = blockIdx.x * WPB + wave;
    const int trA  = wid * 2;
    const int trB  = wid * 2 + 1;
    if (trA >= B) return;
    const bool hasB = (trB < B);

    const int p = lane & 15;   // position within 16-lane DPP row
    const int g = lane >> 4;   // row-group 0..3
    const int godd = g & 1;
    const int jh = g >> 1;     // layer-2 input half

    // ---- one-time per-lane weight gathers in DPP-rotated order ----
    float W1a[16], W1b[16], W2r[16], W3a[16], W3b[16];
    const int r2 = p + 16 * godd;
#pragma unroll
    for (int k = 0; k < 16; ++k) {
        const int c = (p + k) & 15;
        W1a[k] = W1[p * 64 + 16 * g + c];
        W1b[k] = W1[(16 + p) * 64 + 16 * g + c];
        W2r[k] = W2[r2 * 32 + 16 * jh + c];
        W3a[k] = W3[lane * 32 + c];
        W3b[k] = W3[lane * 32 + 16 + c];
    }
#pragma unroll
    for (int k = 0; k < 16; ++k) {
        asm("" : "+v"(W1a[k]));
        asm("" : "+v"(W1b[k]));
        asm("" : "+v"(W2r[k]));
        asm("" : "+v"(W3a[k]));
        asm("" : "+v"(W3b[k]));
    }
    const float b1a = b1[p], b1b = b1[p + 16];
    const float b2r = b2[r2], b3r = b3[lane];

    // Dual f: per-trajectory op sequence is BITWISE IDENTICAL to round 7's
    // single-traj f (same rounding) — output must match round 7 exactly.
    // INVARIANT: cross-lane reductions are symmetric butterflies (shfl_xor)
    // -> bitwise lane-uniform accept/break flags (round-6 lesson).
    auto fd = [&](float uA, float uB, float& rA, float& rB) {
        float aA0 = 0.f, aA1 = 0.f, aA2 = 0.f, aA3 = 0.f;
        float aB0 = 0.f, aB1 = 0.f, aB2 = 0.f, aB3 = 0.f;
        DOT8_LO(aA0, W1a, uA);
        DOT8_LO(aB0, W1a, uB);
        DOT8_HI(aA1, W1a, uA);
        DOT8_HI(aB1, W1a, uB);
        DOT8_LO(aA2, W1b, uA);
        DOT8_LO(aB2, W1b, uB);
        DOT8_HI(aA3, W1b, uA);
        DOT8_HI(aB3, W1b, uB);
        float a1aA = aA0 + aA1, a1bA = aA2 + aA3;
        float a1aB = aB0 + aB1, a1bB = aB2 + aB3;
        {
            float t1 = __shfl_xor(a1aA, 16);
            float t2 = __shfl_xor(a1bA, 16);
            float t3 = __shfl_xor(a1aB, 16);
            float t4 = __shfl_xor(a1bB, 16);
            a1aA += t1; a1bA += t2; a1aB += t3; a1bB += t4;
            t1 = __shfl_xor(a1aA, 32);
            t2 = __shfl_xor(a1bA, 32);
            t3 = __shfl_xor(a1aB, 32);
            t4 = __shfl_xor(a1bB, 32);
            a1aA += t1; a1bA += t2; a1aB += t3; a1bB += t4;
        }
        float h1AA = sp(a1aA + b1a);   // traj A: h1[p]
        float h1BA = sp(a1bA + b1b);   // traj A: h1[16+p]
        float h1AB = sp(a1aB + b1a);   // traj B: h1[p]
        float h1BB = sp(a1bB + b1b);   // traj B: h1[16+p]
        float SA = jh ? h1BA : h1AA;
        float SB = jh ? h1BB : h1AB;
        float a2A0 = 0.f, a2A1 = 0.f, a2B0 = 0.f, a2B1 = 0.f;
        DOT8_LO(a2A0, W2r, SA);
        DOT8_LO(a2B0, W2r, SB);
        DOT8_HI(a2A1, W2r, SA);
        DOT8_HI(a2B1, W2r, SB);
        float a2A = a2A0 + a2A1;
        float a2B = a2B0 + a2B1;
        {
            float t1 = __shfl_xor(a2A, 32);
            float t2 = __shfl_xor(a2B, 32);
            a2A += t1; a2B += t2;
        }
        float h2vA = sp(a2A + b2r);
        float h2vB = sp(a2B + b2r);
        float oA = __shfl_xor(h2vA, 16);
        float oB = __shfl_xor(h2vB, 16);
        float h2AA = godd ? oA : h2vA;     // A: h2[p]
        float h2BA = godd ? h2vA : oA;     // A: h2[16+p]
        float h2AB = godd ? oB : h2vB;     // B: h2[p]
        float h2BB = godd ? h2vB : oB;     // B: h2[16+p]
        float cA0 = 0.f, cA1 = 0.f, dA0 = 0.f, dA1 = 0.f;
        float cB0 = 0.f, cB1 = 0.f, dB0 = 0.f, dB1 = 0.f;
        DOT8_LO(cA0, W3a, h2AA);
        DOT8_LO(cB0, W3a, h2AB);
        DOT8_HI(cA1, W3a, h2AA);
        DOT8_HI(cB1, W3a, h2AB);
        DOT8_LO(dA0, W3b, h2BA);
        DOT8_LO(dB0, W3b, h2BB);
        DOT8_HI(dA1, W3b, h2BA);
        DOT8_HI(dB1, W3b, h2BB);
        rA = ((cA0 + cA1) + (dA0 + dA1)) + b3r;
        rB = ((cB0 + cB1) + (dB0 + dB1)) + b3r;
    };

    int ti = *(const int*)Tptr;
    float Tf = (ti > 0 && ti < 1000000) ? (float)ti : *(const float*)Tptr;
    const float ts_step = Tf / 10.0f;

    float yA = x0s[trA * 64 + lane];
    float yB = hasB ? x0s[trB * 64 + lane] : 0.0f;
    out[trA * 704 + lane] = yA;
    if (hasB) out[trB * 704 + lane] = yB;

    float tA = 0.0f, tB = hasB ? 0.0f : Tf;   // !hasB => B never active
    float dtA = 1e-3f, dtB = 1e-3f;
    int nA = 0, nB = 0;

    float k1A, k1B;
    fd(yA, yB, k1A, k1B);  // FSAL seed

    for (int iv = 1; iv <= 10; ++iv) {
        const float t_target = (iv == 10) ? Tf : ts_step * (float)iv;
        for (int it = 0; it < 64; ++it) {
            const float remA = t_target - tA;
            const float remB = t_target - tB;
            const bool actA = remA > 1e-12f;
            const bool actB = remB > 1e-12f;
            if (!actA && !actB) break;   // wave-uniform
            const float hA = fminf(dtA, fmaxf(remA, 0.0f));
            const float hB = fminf(dtB, fmaxf(remB, 0.0f));

            float k2A, k2B, k3A, k3B, k4A, k4B, k5A, k5B, k6A, k6B, k7A, k7B;
            float aA, aB;
            aA = yA + hA * (A21f * k1A);
            aB = yB + hB * (A21f * k1B);
            fd(aA, aB, k2A, k2B);
            aA = yA + hA * (A31f * k1A + A32f * k2A);
            aB = yB + hB * (A31f * k1B + A32f * k2B);
            fd(aA, aB, k3A, k3B);
            aA = yA + hA * (A41f * k1A + A42f * k2A + A43f * k3A);
            aB = yB + hB * (A41f * k1B + A42f * k2B + A43f * k3B);
            fd(aA, aB, k4A, k4B);
            aA = yA + hA * (A51f * k1A + A52f * k2A + A53f * k3A + A54f * k4A);
            aB = yB + hB * (A51f * k1B + A52f * k2B + A53f * k3B + A54f * k4B);
            fd(aA, aB, k5A, k5B);
            aA = yA + hA * (A61f * k1A + A62f * k2A + A63f * k3A + A64f * k4A + A65f * k5A);
            aB = yB + hB * (A61f * k1B + A62f * k2B + A63f * k3B + A64f * k4B + A65f * k5B);
            fd(aA, aB, k6A, k6B);
            float y5A = yA + hA * (B1f * k1A + B2f * k2A + B3f * k3A + B4f * k4A + B5f * k5A + B6f * k6A);
            float y5B = yB + hB * (B1f * k1B + B2f * k2B + B3f * k3B + B4f * k4B + B5f * k5B + B6f * k6B);
            fd(y5A, y5B, k7A, k7B);
            float errA = hA * (E1f * k1A + E2f * k2A + E3f * k3A + E4f * k4A + E5f * k5A + E6f * k6A + E7f * k7A);
            float errB = hB * (E1f * k1B + E2f * k2B + E3f * k3B + E4f * k4B + E5f * k5B + E6f * k6B + E7f * k7B);

            float sclA = 1e-6f + 1e-3f * fmaxf(fabsf(yA), fabsf(y5A));
            float sclB = 1e-6f + 1e-3f * fmaxf(fabsf(yB), fabsf(y5B));
            float rA_ = errA / sclA;
            float rB_ = errB / sclB;
            float sA = rA_ * rA_;
            float sB = rB_ * rB_;
            // paired symmetric butterflies — bitwise lane-uniform enorms
#pragma unroll
            for (int m = 32; m >= 1; m >>= 1) {
                float ta = __shfl_xor(sA, m);
                float tb = __shfl_xor(sB, m);
                sA += ta; sB += tb;
            }
            float enA = fmaxf(sqrtf(sA * (1.0f / 64.0f)), 1e-10f);
            float enB = fmaxf(sqrtf(sB * (1.0f / 64.0f)), 1e-10f);

            bool accA = enA <= 1.0f;
            bool accB = enB <= 1.0f;
            float facA = fminf(fmaxf(0.9f * exp2f(-0.2f * __log2f(enA)), 0.1f), 5.0f);
            float facB = fminf(fmaxf(0.9f * exp2f(-0.2f * __log2f(enB)), 0.1f), 5.0f);

            if (actA) {
                if (accA) { tA += hA; yA = y5A; k1A = k7A; }
                dtA = fmaxf(hA * facA, 1e-8f);
                ++nA;
            }
            if (actB) {
                if (accB) { tB += hB; yB = y5B; k1B = k7B; }
                dtB = fmaxf(hB * facB, 1e-8f);
                ++nB;
            }
        }
        out[trA * 704 + iv * 64 + lane] = yA;
        if (hasB) out[trB * 704 + iv * 64 + lane] = yB;
    }

    if (lane == 0) atomicAdd(out + (out_size - 1), (float)(nA + (hasB ? nB : 0)));
}

__global__ void init_n(float* p) { *p = 0.0f; }

extern "C" void kernel_launch(void* const* d_in, const int* in_sizes, int n_in,
                              void* d_out, int out_size, void* d_ws, size_t ws_size,
                              hipStream_t stream) {
    const float* x0s = (const float*)d_in[0];
    const float* W1  = (const float*)d_in[1];
    const float* b1  = (const float*)d_in[2];
    const float* W2  = (const float*)d_in[3];
    const float* b2  = (const float*)d_in[4];
    const float* W3  = (const float*)d_in[5];
    const float* b3  = (const float*)d_in[6];
    const void*  Tp  = d_in[7];
    float* out = (float*)d_out;

    const int B = in_sizes[0] / 64;
    const int nwaves = (B + 1) / 2;
    const int grid = (nwaves + WPB - 1) / WPB;

    init_n<<<1, 1, 0, stream>>>(out + (out_size - 1));
    ode_kernel<<<grid, 256, 0, stream>>>(x0s, W1, b1, W2, b2, W3, b3, Tp,
                                         out, out_size, B);
}